// Round 4
// baseline (711.237 us; speedup 1.0000x reference)
//
#include <hip/hip_runtime.h>
#include <hip/hip_bf16.h>

// Problem constants
#define NB    2048   // batch
#define SS    200    // seq len
#define NTIL  13     // s-tiles of 16 (208 padded)
#define DSEQ  256
#define DITEM 64
#define AA    128    // attn dim (H=1, HD=128)

typedef __bf16 bf16x8 __attribute__((ext_vector_type(8)));
typedef float  f32x4  __attribute__((ext_vector_type(4)));

typedef const __attribute__((address_space(1))) void gvoid_t;
typedef __attribute__((address_space(3))) void lvoid_t;

__device__ __forceinline__ float prelu_f(float x, float a) { return x >= 0.f ? x : a * x; }

// 16-lane (rg-group) sum via DPP row_ror — VALU pipe only.
#define ROR_F(x, n) __int_as_float(__builtin_amdgcn_update_dpp(0, __float_as_int(x), 0x120 + (n), 0xf, 0xf, true))
__device__ __forceinline__ float row_sum16(float x) {
    x += ROR_F(x, 1); x += ROR_F(x, 2); x += ROR_F(x, 4); x += ROR_F(x, 8);
    return x;
}

// ---------------- prep: W_k|W_v -> bf16 [256 rows][512B], XOR-swizzled within rows
// element (a,d) stored at byte (d*2) ^ ((a&7)<<4) of row a  (bits<4 preserved)
__global__ void prep_kernel(const float* __restrict__ Wk, const float* __restrict__ Wv,
                            __hip_bfloat16* __restrict__ Wb) {
    int idx = blockIdx.x * 256 + threadIdx.x;   // 256 blocks -> 65536
    int a = idx >> 8, d = idx & 255;
    float v = (a < 128) ? Wk[a * 256 + d] : Wv[(a - 128) * 256 + d];
    int boff = (d * 2) ^ ((a & 7) << 4);
    Wb[a * 256 + (boff >> 1)] = __float2bfloat16(v);
}

// ---------------- main: one WAVE per batch row; 8 waves/block; weights in LDS
__global__ __launch_bounds__(512, 2) void pool_main(
    const float* __restrict__ X,      // [2048,200,256]
    const int*   __restrict__ maskp,  // [2048,200] 1 = pad
    const float* __restrict__ temb,   // [2048,64]
    const float* __restrict__ Wq,     // [128,64]
    const float* __restrict__ Wker,   // [128,128]
    const float* __restrict__ ffnW,   // [256,128]
    const float* __restrict__ ffnb,   // [256]
    const float* __restrict__ prelu_a,
    const __hip_bfloat16* __restrict__ Wb,  // ws: swizzled bf16 weights [256][256]
    float* __restrict__ out)          // [2048*256] ffn, then [2048*200] attn
{
    __shared__ __hip_bfloat16 Wlds[256 * 256];   // 128 KB (rows 0..127 = K, 128..255 = V)
    __shared__ float slab[8][656];               // per-wave private scratch

    const int tid  = threadIdx.x;
    const int w    = tid >> 6;
    const int lane = tid & 63;
    const int c    = lane & 15;       // A-row (s within tile) == D-col (a-col within ct)
    const int rg   = lane >> 4;       // k-group / D-row-group
    const int b    = blockIdx.x * 8 + w;
    float* S = slab[w];
    const float pa = *prelu_a;
    const float inv_scale = 0.08838834764831845f;  // 1/sqrt(128)

    enum { SCORE_O = 0, TO = 208, QO = 272, UO = 400, OV_O = 528 };

    // ---- async copy of pre-swizzled weights into LDS (linear copy)
    {
        const char* wsrc = (const char*)Wb;
        char* wdst = (char*)Wlds;
        #pragma unroll
        for (int i = 0; i < 16; i++) {
            __builtin_amdgcn_global_load_lds((gvoid_t*)(wsrc + i * 8192 + tid * 16),
                                             (lvoid_t*)(wdst + i * 8192 + w * 1024), 16, 0, 0);
        }
    }

    // ---- issue X tile 0 into registers (prefetch)
    f32x4 st[16];
    {
        int r = 0 * 16 + c; r = r < SS ? r : SS - 1;
        const float* xp = X + ((size_t)b * SS + r) * DSEQ + rg * 8;
        #pragma unroll
        for (int k = 0; k < 8; k++) {
            st[2 * k]     = *reinterpret_cast<const f32x4*>(xp + k * 32);
            st[2 * k + 1] = *reinterpret_cast<const f32x4*>(xp + k * 32 + 4);
        }
    }

    // ---- per-wave Q and u (global weights + private LDS slab; no cross-wave sync)
    S[TO + lane] = temb[(size_t)b * DITEM + lane];
    asm volatile("s_waitcnt lgkmcnt(0)" ::: "memory");
    {
        float a0 = 0.f, a1 = 0.f;
        #pragma unroll
        for (int d4 = 0; d4 < 16; d4++) {
            f32x4 tv = *reinterpret_cast<const f32x4*>(&S[TO + d4 * 4]);
            f32x4 w0 = *reinterpret_cast<const f32x4*>(Wq + (size_t)lane * DITEM + d4 * 4);
            f32x4 w1 = *reinterpret_cast<const f32x4*>(Wq + (size_t)(lane + 64) * DITEM + d4 * 4);
            a0 += w0[0]*tv[0] + w0[1]*tv[1] + w0[2]*tv[2] + w0[3]*tv[3];
            a1 += w1[0]*tv[0] + w1[1]*tv[1] + w1[2]*tv[2] + w1[3]*tv[3];
        }
        S[QO + lane]      = prelu_f(a0, pa);
        S[QO + 64 + lane] = prelu_f(a1, pa);
    }
    asm volatile("s_waitcnt lgkmcnt(0)" ::: "memory");
    {
        float a0 = 0.f, a1 = 0.f;
        #pragma unroll
        for (int d4 = 0; d4 < 32; d4++) {
            f32x4 qv = *reinterpret_cast<const f32x4*>(&S[QO + d4 * 4]);
            f32x4 w0 = *reinterpret_cast<const f32x4*>(Wker + (size_t)lane * AA + d4 * 4);
            f32x4 w1 = *reinterpret_cast<const f32x4*>(Wker + (size_t)(lane + 64) * AA + d4 * 4);
            a0 += w0[0]*qv[0] + w0[1]*qv[1] + w0[2]*qv[2] + w0[3]*qv[3];
            a1 += w1[0]*qv[0] + w1[1]*qv[1] + w1[2]*qv[2] + w1[3]*qv[3];
        }
        S[UO + lane]      = a0;
        S[UO + 64 + lane] = a1;
    }
    asm volatile("s_waitcnt lgkmcnt(0)" ::: "memory");
    float uw[8];
    #pragma unroll
    for (int ct = 0; ct < 8; ct++) uw[ct] = S[UO + ct * 16 + c];

    __syncthreads();   // the ONLY block barrier: weights now visible

    // ---- fully independent per-wave main loop
    float m = -INFINITY, l = 0.f;
    float oacc[8] = {0.f,0.f,0.f,0.f,0.f,0.f,0.f,0.f};
    const char* wbase = (const char*)Wlds;
    const int rswz = (c & 7) << 4;
    const int cb   = c * 512;

    for (int t = 0; t < NTIL; t++) {
        // convert tile t to bf16 A-fragments (waits on the prefetched loads here)
        bf16x8 af[8];
        #pragma unroll
        for (int k = 0; k < 8; k++) {
            f32x4 lo = st[2 * k], hi = st[2 * k + 1];
            bf16x8 v;
            v[0]=(__bf16)lo[0]; v[1]=(__bf16)lo[1]; v[2]=(__bf16)lo[2]; v[3]=(__bf16)lo[3];
            v[4]=(__bf16)hi[0]; v[5]=(__bf16)hi[1]; v[6]=(__bf16)hi[2]; v[7]=(__bf16)hi[3];
            af[k] = v;
        }
        // prefetch tile t+1 (latency covered by the 128 MFMA + 128 LDS reads below)
        if (t + 1 < NTIL) {
            int r = (t + 1) * 16 + c; r = r < SS ? r : SS - 1;
            const float* xp = X + ((size_t)b * SS + r) * DSEQ + rg * 8;
            #pragma unroll
            for (int k = 0; k < 8; k++) {
                st[2 * k]     = *reinterpret_cast<const f32x4*>(xp + k * 32);
                st[2 * k + 1] = *reinterpret_cast<const f32x4*>(xp + k * 32 + 4);
            }
        }

        // ---- K phase: scores
        float pr[4] = {0.f, 0.f, 0.f, 0.f};
        #pragma unroll
        for (int cp = 0; cp < 4; cp++) {
            f32x4 aKa = {0.f,0.f,0.f,0.f}, aKb = {0.f,0.f,0.f,0.f};
            const char* ba = wbase + (2 * cp) * 8192 + cb;
            const char* bb = ba + 8192;
            #pragma unroll
            for (int k = 0; k < 8; k++) {
                const int o = (k * 64 + rg * 16) ^ rswz;
                bf16x8 wa = *reinterpret_cast<const bf16x8*>(ba + o);
                bf16x8 wbg = *reinterpret_cast<const bf16x8*>(bb + o);
                aKa = __builtin_amdgcn_mfma_f32_16x16x32_bf16(af[k], wa,  aKa, 0, 0, 0);
                aKb = __builtin_amdgcn_mfma_f32_16x16x32_bf16(af[k], wbg, aKb, 0, 0, 0);
            }
            #pragma unroll
            for (int i = 0; i < 4; i++)
                pr[i] += prelu_f(aKa[i], pa) * uw[2*cp] + prelu_f(aKb[i], pa) * uw[2*cp+1];
        }
        #pragma unroll
        for (int i = 0; i < 4; i++) pr[i] = row_sum16(pr[i]);

        // ---- mask + online softmax (per-lane rows s = t*16 + rg*4 + i)
        const int sb  = t * 16 + rg * 4;
        const int sbc = sb > 196 ? 196 : sb;
        const int4 mv = *reinterpret_cast<const int4*>(maskp + (size_t)b * SS + sbc);
        float sc[4];
        #pragma unroll
        for (int i = 0; i < 4; i++) {
            int s = sb + i;
            int mi = (i == 0) ? mv.x : (i == 1) ? mv.y : (i == 2) ? mv.z : mv.w;
            sc[i] = (s >= SS || mi != 0) ? -1e9f : pr[i] * inv_scale;
        }
        if (c == 0) *reinterpret_cast<f32x4*>(&S[SCORE_O + sb]) = (f32x4){sc[0], sc[1], sc[2], sc[3]};

        float tmax = fmaxf(fmaxf(sc[0], sc[1]), fmaxf(sc[2], sc[3]));
        tmax = fmaxf(tmax, __shfl_xor(tmax, 16, 64));
        tmax = fmaxf(tmax, __shfl_xor(tmax, 32, 64));
        const float nm = fmaxf(m, tmax);
        const float fs = __expf(m - nm);
        float e[4], lsum = 0.f;
        #pragma unroll
        for (int i = 0; i < 4; i++) { e[i] = __expf(sc[i] - nm); lsum += e[i]; }
        lsum += __shfl_xor(lsum, 16, 64);
        lsum += __shfl_xor(lsum, 32, 64);
        l = l * fs + lsum; m = nm;
        #pragma unroll
        for (int ct = 0; ct < 8; ct++) oacc[ct] *= fs;

        // ---- V phase: weighted accumulation (consume D immediately)
        #pragma unroll
        for (int cp = 0; cp < 4; cp++) {
            f32x4 aVa = {0.f,0.f,0.f,0.f}, aVb = {0.f,0.f,0.f,0.f};
            const char* ba = wbase + 65536 + (2 * cp) * 8192 + cb;
            const char* bb = ba + 8192;
            #pragma unroll
            for (int k = 0; k < 8; k++) {
                const int o = (k * 64 + rg * 16) ^ rswz;
                bf16x8 wa = *reinterpret_cast<const bf16x8*>(ba + o);
                bf16x8 wbg = *reinterpret_cast<const bf16x8*>(bb + o);
                aVa = __builtin_amdgcn_mfma_f32_16x16x32_bf16(af[k], wa,  aVa, 0, 0, 0);
                aVb = __builtin_amdgcn_mfma_f32_16x16x32_bf16(af[k], wbg, aVb, 0, 0, 0);
            }
            #pragma unroll
            for (int i = 0; i < 4; i++) {
                oacc[2*cp]   += e[i] * prelu_f(aVa[i], pa);
                oacc[2*cp+1] += e[i] * prelu_f(aVb[i], pa);
            }
        }
    }

    // ---- finalize: cross-rg reduce of oacc, normalize, outputs (all per-wave)
    #pragma unroll
    for (int ct = 0; ct < 8; ct++) {
        oacc[ct] += __shfl_xor(oacc[ct], 16, 64);
        oacc[ct] += __shfl_xor(oacc[ct], 32, 64);
    }
    const float invl = 1.0f / l;
    S[OV_O + (rg * 2) * 16 + c]     = oacc[rg * 2]     * invl;
    S[OV_O + (rg * 2 + 1) * 16 + c] = oacc[rg * 2 + 1] * invl;
    asm volatile("s_waitcnt lgkmcnt(0)" ::: "memory");

    // attn output
    #pragma unroll
    for (int j = 0; j < 4; j++) {
        int s = lane + j * 64;
        if (s < SS)
            out[(size_t)NB * DSEQ + (size_t)b * SS + s] = __expf(S[SCORE_O + s] - m) * invl;
    }

    // FFN: out[o] = prelu(b[o] + sum_a ov[a]*ffnW[o][a]), o = lane + j*64
    float fa[4];
    #pragma unroll
    for (int j = 0; j < 4; j++) fa[j] = ffnb[lane + j * 64];
    #pragma unroll
    for (int a4 = 0; a4 < 32; a4++) {
        f32x4 ov = *reinterpret_cast<const f32x4*>(&S[OV_O + a4 * 4]);
        #pragma unroll
        for (int j = 0; j < 4; j++) {
            f32x4 wv4 = *reinterpret_cast<const f32x4*>(ffnW + (size_t)(lane + j * 64) * AA + a4 * 4);
            fa[j] += wv4[0]*ov[0] + wv4[1]*ov[1] + wv4[2]*ov[2] + wv4[3]*ov[3];
        }
    }
    #pragma unroll
    for (int j = 0; j < 4; j++)
        out[(size_t)b * DSEQ + lane + j * 64] = prelu_f(fa[j], pa);
}

extern "C" void kernel_launch(void* const* d_in, const int* in_sizes, int n_in,
                              void* d_out, int out_size, void* d_ws, size_t ws_size,
                              hipStream_t stream) {
    const float* X    = (const float*)d_in[0];
    const int*   mask = (const int*)  d_in[1];
    const float* temb = (const float*)d_in[2];
    const float* Wq   = (const float*)d_in[3];
    const float* Wk   = (const float*)d_in[4];
    const float* Wv   = (const float*)d_in[5];
    const float* Wker = (const float*)d_in[6];
    const float* ffnW = (const float*)d_in[7];
    const float* ffnb = (const float*)d_in[8];
    const float* pa   = (const float*)d_in[9];
    float* out = (float*)d_out;

    __hip_bfloat16* Wb = (__hip_bfloat16*)d_ws;

    prep_kernel<<<256, 256, 0, stream>>>(Wk, Wv, Wb);
    pool_main<<<NB / 8, 512, 0, stream>>>(X, mask, temb, Wq, Wker, ffnW, ffnb, pa, Wb, out);
}